// Round 5
// baseline (1186.994 us; speedup 1.0000x reference)
//
#include <hip/hip_runtime.h>
#include <math.h>

// ---------------- problem constants ----------------
constexpr int kH = 48, kW = 64, kHW = 3072, kC = 256;
constexpr int kHidden = 128, kCtx = 64;
constexpr int kP = 81, kCorrDim = 324;  // 81*4
constexpr int kNS = 37, kIters = 4;
constexpr int kGin = kHidden + kCorrDim + kCtx;  // 516
constexpr int kCinPad = 544;                     // 17*32
constexpr int kStepsBig = 17 * 9;                // 153
constexpr int kStepsH = 4 * 9;                   // 36

// box-filtered pyramid (padded +10 each dim), per source pixel:
// L0 74x58, L1 42x34, L2 26x22, L3 18x16 -> 6580 entries
constexpr int kSB0 = 0, kSB1 = 4292, kSB2 = 5720, kSB3 = 6292, kSBTot = 6580;

// ---------------- workspace layout ----------------
// ushort-unit offsets
constexpr size_t U_CORR0 = 0;                                   // 3072*3072
constexpr size_t U_CORR1 = U_CORR0 + (size_t)kHW * 3072;        // 3072*768
constexpr size_t U_CORR2 = U_CORR1 + (size_t)kHW * 768;         // 3072*192
constexpr size_t U_CORR3 = U_CORR2 + (size_t)kHW * 192;         // 3072*48
constexpr size_t U_END0  = U_CORR3 + (size_t)kHW * 48;          // 12533760
// float-unit offsets
constexpr size_t F_X     = U_END0 / 2;                          // 3072*3
constexpr size_t F_H     = F_X + (size_t)kHW * 3;               // 128*3072
constexpr size_t F_ZPRE  = F_H + (size_t)kHidden * kHW;         // 128*3072
constexpr size_t F_END1  = F_ZPRE + (size_t)kHidden * kHW;
// ushort buffers
constexpr size_t U_BUFT  = F_END1 * 2;                          // 3072*544
constexpr size_t U_RHT   = U_BUFT + (size_t)kHW * kCinPad;      // 3072*128
constexpr size_t U_PZR   = U_RHT + (size_t)kHW * kHidden;       // 153*256*32
constexpr size_t U_PQ    = U_PZR + (size_t)kStepsBig * 256 * 32;
constexpr size_t U_PH    = U_PQ + (size_t)kStepsBig * 128 * 32;
constexpr size_t U_END2  = U_PH + (size_t)kStepsH * 128 * 32;
// small float scalars
constexpr size_t F_BZR   = (U_END2 + 2) / 2;  // 256
constexpr size_t F_CONF  = F_BZR + 256;       // 64
constexpr size_t F_TK    = F_CONF + 64;       // 16
constexpr size_t F_POSE  = F_TK + 16;         // 16
constexpr size_t F_FEAT  = F_POSE + 16;       // 128
constexpr size_t F_END3  = F_FEAT + 128;
// transposed bf16 feature maps (setup-only) -- Sbox overlays them afterwards
constexpr size_t U_FDT   = F_END3 * 2;                   // 3072*256
constexpr size_t U_QT    = U_FDT + (size_t)kHW * kC;     // 3072*256
constexpr size_t U_SBOX  = U_FDT;                        // 3072*6580 (reuses fdT/qT)

typedef __attribute__((ext_vector_type(8))) short short8;
typedef __attribute__((ext_vector_type(4))) float f32x4;

__device__ inline unsigned short f2b(float f) {
  unsigned int u = __float_as_uint(f);
  unsigned int r = u + 0x7FFF + ((u >> 16) & 1);
  return (unsigned short)(r >> 16);
}
__device__ inline float b2f(unsigned short u) {
  return __uint_as_float(((unsigned int)u) << 16);
}
__device__ inline int clampi(int v, int lo, int hi) { return min(max(v, lo), hi); }

// ---------------- sample templates ----------------
__constant__ float c_rot[12][3] = {
  {0,0,0},{0,0,0},{0,0,0},{0,0,0},{0,0,0},{0,0,0},
  {1,0,0},{-1,0,0},{0,1,0},{0,-1,0},{0,0,1},{0,0,-1}};
__constant__ float c_trs[12][3] = {
  {1,0,0},{-1,0,0},{0,1,0},{0,-1,0},{0,0,1},{0,0,-1},
  {0,0,0},{0,0,0},{0,0,0},{0,0,0},{0,0,0},{0,0,0}};

// ---------------- device helpers ----------------
__device__ inline void d_qmul(const float* q, const float* r, float* o) {
  o[0] = q[0]*r[0] - q[1]*r[1] - q[2]*r[2] - q[3]*r[3];
  o[1] = q[0]*r[1] + q[1]*r[0] + q[2]*r[3] - q[3]*r[2];
  o[2] = q[0]*r[2] - q[1]*r[3] + q[2]*r[0] + q[3]*r[1];
  o[3] = q[0]*r[3] + q[1]*r[2] - q[2]*r[1] + q[3]*r[0];
}
__device__ inline void d_qapply(const float* q, const float* v, float* o) {
  float a0 = -q[1]*v[0] - q[2]*v[1] - q[3]*v[2];
  float a1 =  q[0]*v[0] + q[2]*v[2] - q[3]*v[1];
  float a2 =  q[0]*v[1] - q[1]*v[2] + q[3]*v[0];
  float a3 =  q[0]*v[2] + q[1]*v[1] - q[2]*v[0];
  o[0] = -a0*q[1] + a1*q[0] - a2*q[3] + a3*q[2];
  o[1] = -a0*q[2] + a1*q[3] + a2*q[0] - a3*q[1];
  o[2] = -a0*q[3] - a1*q[2] + a2*q[1] + a3*q[0];
}
__device__ inline void d_intr(const float* intr, float& fx, float& fy, float& cx, float& cy) {
  fx = 60.f + 40.f*intr[0];
  fy = 60.f + 40.f*intr[1];
  cx = 32.f + 4.f*(intr[2] - 0.5f);
  cy = 24.f + 4.f*(intr[3] - 0.5f);
}
__device__ inline void sample_Rt(int t, const float* __restrict__ pose, float* S) {
  float qc[4] = {pose[0], pose[1], pose[2], pose[3]};
  float tc[3] = {pose[4], pose[5], pose[6]};
  float dq[4], dt[3];
  if (t == 36) {
    dq[0] = 1.f; dq[1] = dq[2] = dq[3] = 0.f;
    dt[0] = dt[1] = dt[2] = 0.f;
  } else {
    int j = t / 3, k = t % 3;
    float sc = (k == 0) ? 0.25f : ((k == 1) ? 1.f : 4.f);
    float rx = c_rot[j][0], ry = c_rot[j][1], rz = c_rot[j][2];
    float nrm = sqrtf(rx*rx + ry*ry + rz*rz);
    float axn = fmaxf(nrm, 1e-8f);
    float ax = rx / axn, ay = ry / axn, az = rz / axn;
    float ha = 0.02f * sc * 0.5f;
    float sh = sinf(ha), ch = cosf(ha);
    dq[0] = ch; dq[1] = ax * sh; dq[2] = ay * sh; dq[3] = az * sh;
    dt[0] = c_trs[j][0] * (0.02f * sc);
    dt[1] = c_trs[j][1] * (0.02f * sc);
    dt[2] = c_trs[j][2] * (0.02f * sc);
  }
  float qn[4];
  d_qmul(qc, dq, qn);
  float inv = 1.f / sqrtf(qn[0]*qn[0] + qn[1]*qn[1] + qn[2]*qn[2] + qn[3]*qn[3]);
  qn[0] *= inv; qn[1] *= inv; qn[2] *= inv; qn[3] *= inv;
  float tr[3];
  d_qapply(qc, dt, tr);
  float w = qn[0], x = qn[1], y = qn[2], z = qn[3];
  S[0] = 1.f - 2.f*(y*y + z*z); S[1] = 2.f*(x*y - w*z);       S[2] = 2.f*(x*z + w*y);
  S[3] = 2.f*(x*y + w*z);       S[4] = 1.f - 2.f*(x*x + z*z); S[5] = 2.f*(y*z - w*x);
  S[6] = 2.f*(x*z - w*y);       S[7] = 2.f*(y*z + w*x);       S[8] = 1.f - 2.f*(x*x + y*y);
  S[9]  = tc[0] + tr[0];
  S[10] = tc[1] + tr[1];
  S[11] = tc[2] + tr[2];
}
__device__ inline void project_uv(const float* S, const float* Xp, const float* intr,
                                  float& u, float& v) {
  float xc0 = S[0]*Xp[0] + S[1]*Xp[1] + S[2]*Xp[2] + S[9];
  float xc1 = S[3]*Xp[0] + S[4]*Xp[1] + S[5]*Xp[2] + S[10];
  float xc2 = S[6]*Xp[0] + S[7]*Xp[1] + S[8]*Xp[2] + S[11];
  float z = fmaxf(xc2, 0.1f);
  float fx, fy, cx, cy;
  d_intr(intr, fx, fy, cx, cy);
  u = fx * xc0 / z + cx;
  v = fy * xc1 / z + cy;
}

// ---------------- init ----------------
__global__ void init_k(const float* __restrict__ ctx, const float* __restrict__ bz,
                       const float* __restrict__ br, const float* __restrict__ depth,
                       const float* __restrict__ intr, float* __restrict__ h,
                       unsigned short* __restrict__ bufT, float* __restrict__ bzr,
                       float* __restrict__ X, float* __restrict__ conf,
                       float* __restrict__ feat, float* __restrict__ pose) {
  int idx = blockIdx.x * blockDim.x + threadIdx.x;
  if (idx < kHidden * kHW) {
    h[idx] = 0.f;
    int p = idx >> 7, c = idx & 127;
    bufT[(size_t)p * kCinPad + c] = 0;
  }
  if (idx < kHW * 92) {  // ctx cols 452..515 + zero pad 516..543
    int p = idx / 92, c = idx % 92;
    unsigned short v = 0;
    if (c < 64) v = f2b(ctx[(size_t)c * kHW + p]);
    bufT[(size_t)p * kCinPad + 452 + c] = v;
  }
  if (idx < kHW) {
    float fx, fy, cx, cy;
    d_intr(intr, fx, fy, cx, cy);
    float d = 4.f + 20.f * depth[idx];
    float u = (float)(idx % kW), v = (float)(idx / kW);
    X[idx*3+0] = (u - cx) / fx * d;
    X[idx*3+1] = (v - cy) / fy * d;
    X[idx*3+2] = d;
  }
  if (idx < 256) bzr[idx] = (idx < 128) ? bz[idx] : br[idx - 128];
  if (idx < 64) conf[idx] = 0.f;
  if (idx < 128) feat[idx] = 0.f;
  if (idx == 0) {
    pose[0] = 1.f;
    for (int j = 1; j < 7; ++j) pose[j] = 0.f;
  }
}

// ---------------- weight prepack (tap-major) ----------------
__global__ void pack_k(const float* __restrict__ W0, const float* __restrict__ W1,
                       int ocSplit, int OC, int nsteps, int nchunks, int Cin,
                       unsigned short* __restrict__ P) {
  int idx = blockIdx.x * blockDim.x + threadIdx.x;
  int total = nsteps * OC * 4;
  if (idx >= total) return;
  int g = idx & 3;
  int oc = (idx >> 2) % OC;
  int s = idx / (OC * 4);
  int tap = s / nchunks, cc = s % nchunks;
  union { unsigned short u[8]; uint4 q; } v;
#pragma unroll
  for (int j = 0; j < 8; ++j) {
    int ci = cc * 32 + g * 8 + j;
    float w = 0.f;
    if (ci < Cin)
      w = (oc < ocSplit) ? W0[((size_t)oc * Cin + ci) * 9 + tap]
                         : W1[((size_t)(oc - ocSplit) * Cin + ci) * 9 + tap];
    v.u[j] = f2b(w);
  }
  *(uint4*)&P[(size_t)idx * 8] = v.q;
}

// ---------------- fp32 [C][HW] -> bf16 [HW][C] transpose ----------------
__global__ __launch_bounds__(256) void t_bf16_k(const float* __restrict__ src,
                                                unsigned short* __restrict__ dst) {
  __shared__ float t[64][65];
  const int tid = threadIdx.x;
  const int p0 = blockIdx.x * 64, c0 = blockIdx.y * 64;
  const int tx = tid & 63, ty = tid >> 6;
  for (int cl = ty; cl < 64; cl += 4)
    t[cl][tx] = src[(size_t)(c0 + cl) * kHW + p0 + tx];
  __syncthreads();
  for (int pl = ty; pl < 64; pl += 4)
    dst[(size_t)(p0 + pl) * kC + c0 + tx] = f2b(t[tx][pl]);
}

// ---------------- corr GEMM via MFMA -> bf16 pyramid L0 ----------------
__global__ __launch_bounds__(256) void corr_mfma_k(const unsigned short* __restrict__ fdT,
                                                   const unsigned short* __restrict__ qT,
                                                   unsigned short* __restrict__ Cg) {
  const int tid = threadIdx.x;
  const int wv = tid >> 6, lane = tid & 63;
  const int m = lane & 15, kg = lane >> 4;
  const int i0 = blockIdx.y * 128 + wv * 32;
  const int q0 = blockIdx.x * 128;

  f32x4 acc[2][8];
#pragma unroll
  for (int t = 0; t < 2; ++t)
#pragma unroll
    for (int u = 0; u < 8; ++u) acc[t][u] = (f32x4){0.f, 0.f, 0.f, 0.f};

#pragma unroll
  for (int kc = 0; kc < 8; ++kc) {
    const int kb = kc * 32 + kg * 8;
    short8 a[2], b[8];
#pragma unroll
    for (int t = 0; t < 2; ++t)
      a[t] = *(const short8*)&fdT[(size_t)(i0 + t * 16 + m) * kC + kb];
#pragma unroll
    for (int u = 0; u < 8; ++u)
      b[u] = *(const short8*)&qT[(size_t)(q0 + u * 16 + m) * kC + kb];
#pragma unroll
    for (int t = 0; t < 2; ++t)
#pragma unroll
      for (int u = 0; u < 8; ++u)
        acc[t][u] = __builtin_amdgcn_mfma_f32_16x16x32_bf16(a[t], b[u], acc[t][u], 0, 0, 0);
  }
  const float S = 0.0625f;
#pragma unroll
  for (int t = 0; t < 2; ++t)
#pragma unroll
    for (int u = 0; u < 8; ++u)
#pragma unroll
      for (int r = 0; r < 4; ++r)
        Cg[(size_t)(i0 + t * 16 + kg * 4 + r) * kHW + q0 + u * 16 + m] = f2b(acc[t][u][r] * S);
}

// ---------------- 2x2 avg pool (bf16) ----------------
__global__ void pool2_k(const unsigned short* __restrict__ in,
                        unsigned short* __restrict__ out, int Hi, int Wi) {
  int Ho = Hi / 2, Wo = Wi / 2;
  int total = kHW * Ho * Wo;
  int idx = blockIdx.x * blockDim.x + threadIdx.x;
  if (idx >= total) return;
  int i = idx / (Ho * Wo);
  int r = idx % (Ho * Wo);
  int y = r / Wo, x = r % Wo;
  const unsigned short* p = in + (size_t)i * Hi * Wi;
  float v = 0.25f * (b2f(p[(2*y)*Wi + 2*x]) + b2f(p[(2*y)*Wi + 2*x + 1]) +
                     b2f(p[(2*y+1)*Wi + 2*x]) + b2f(p[(2*y+1)*Wi + 2*x + 1]));
  out[idx] = f2b(v);
}

// ---------------- box filter build: horizontal 9-sum -> Sbox rows 0..Hl-1 ----------------
// thread = (pixel, pyramid row). out H(a,y) = sum_{dx=-4..4} P~(a+dx,y), a in [-5, Wl+4]
__global__ __launch_bounds__(256) void boxh_k(const unsigned short* __restrict__ corr0,
                                              const unsigned short* __restrict__ corr1,
                                              const unsigned short* __restrict__ corr2,
                                              const unsigned short* __restrict__ corr3,
                                              unsigned short* __restrict__ Sbox) {
  const int idx = blockIdx.x * blockDim.x + threadIdx.x;  // 3072*90
  const int i = idx / 90, r = idx % 90;
  int lvl, y;
  if (r < 48)      { lvl = 0; y = r; }
  else if (r < 72) { lvl = 1; y = r - 48; }
  else if (r < 84) { lvl = 2; y = r - 72; }
  else             { lvl = 3; y = r - 84; }
  const int Wl = kW >> lvl, Hl = kH >> lvl;
  const unsigned short* base =
      (lvl == 0) ? corr0 : (lvl == 1) ? corr1 : (lvl == 2) ? corr2 : corr3;
  const int so = (lvl == 0) ? kSB0 : (lvl == 1) ? kSB1 : (lvl == 2) ? kSB2 : kSB3;
  const unsigned short* row = base + (size_t)i * (Hl * Wl) + y * Wl;
  unsigned short* out = Sbox + (size_t)i * kSBTot + so + y * (Wl + 10);
  float sum = 0.f;
  for (int a = -5; a <= Wl + 4; ++a) {
    int ir = a + 4;
    if (ir >= 0 && ir < Wl) sum += b2f(row[ir]);
    int il = a - 5;
    if (il >= 0 && il < Wl) sum -= b2f(row[il]);
    out[a + 5] = f2b(sum);
  }
}

// ---------------- box filter build: vertical 9-sum, in-place per column ----------------
// thread = (pixel, padded column). descending-b sliding sum; writes rows 0..Hl+9.
__global__ __launch_bounds__(256) void boxv_k(unsigned short* __restrict__ Sbox) {
  const int idx = blockIdx.x * blockDim.x + threadIdx.x;  // 3072*160
  const int i = idx / 160, c = idx % 160;
  int lvl, a;
  if (c < 74)       { lvl = 0; a = c; }
  else if (c < 116) { lvl = 1; a = c - 74; }
  else if (c < 142) { lvl = 2; a = c - 116; }
  else              { lvl = 3; a = c - 142; }
  const int Wl = kW >> lvl, Hl = kH >> lvl, Wp = Wl + 10;
  const int so = (lvl == 0) ? kSB0 : (lvl == 1) ? kSB1 : (lvl == 2) ? kSB2 : kSB3;
  unsigned short* col = Sbox + (size_t)i * kSBTot + so + a;
  float sum = 0.f;  // S(b) = sum_{r=b-4..b+4} H~(r); start b = Hl+4 -> 0
  for (int b = Hl + 4; b >= -5; --b) {
    // write S(b) at row b+5 (clobbers H row b+5, no longer needed)
    float sv = sum;
    // prepare sum for b-1: += H~(b-5) - H~(b+4)  (reads below current write floor)
    int r1 = b - 5, r2 = b + 4;
    float h1 = (r1 >= 0 && r1 < Hl) ? b2f(col[(size_t)r1 * Wp]) : 0.f;
    float h2 = (r2 >= 0 && r2 < Hl) ? b2f(col[(size_t)r2 * Wp]) : 0.f;
    col[(size_t)(b + 5) * Wp] = f2b(sv);
    sum += h1 - h2;
  }
}

// ---------------- conf: one thread per (sample, pixel); 16 Sbox reads ----------------
__global__ __launch_bounds__(256) void conf_k(const unsigned short* __restrict__ Sbox,
                                              const float* __restrict__ X,
                                              const float* __restrict__ pose,
                                              const float* __restrict__ intr,
                                              float* __restrict__ conf) {
  const int idx = blockIdx.x * 256 + threadIdx.x;  // n*3072 + i, 37*3072 total
  const int n = idx / kHW, i = idx - n * kHW;
  float S[12];
  sample_Rt(n, pose, S);
  float Xp[3] = {X[i*3], X[i*3+1], X[i*3+2]};
  float u, v;
  project_uv(S, Xp, intr, u, v);
  const unsigned short* sb = Sbox + (size_t)i * kSBTot;
  float tot = 0.f;
#pragma unroll
  for (int l = 0; l < 4; ++l) {
    const int Wp = (kW >> l) + 10, Hp = (kH >> l) + 10;
    const int so = (l == 0) ? kSB0 : (l == 1) ? kSB1 : (l == 2) ? kSB2 : kSB3;
    const float s = (float)(1 << l);
    const float bx = u / s, by = v / s;
    const float fbx = floorf(bx), fby = floorf(by);
    const int x0 = (int)fbx, y0 = (int)fby;
    const float fx = bx - fbx, fy = by - fby;
    const int xa = clampi(x0 + 5, 0, Wp - 1), xb = clampi(x0 + 6, 0, Wp - 1);
    const int ya = clampi(y0 + 5, 0, Hp - 1), yb = clampi(y0 + 6, 0, Hp - 1);
    const float s00 = b2f(sb[so + ya * Wp + xa]), s10 = b2f(sb[so + ya * Wp + xb]);
    const float s01 = b2f(sb[so + yb * Wp + xa]), s11 = b2f(sb[so + yb * Wp + xb]);
    tot += (1.f - fx) * (1.f - fy) * s00 + fx * (1.f - fy) * s10 +
           (1.f - fx) * fy * s01 + fx * fy * s11;
  }
#pragma unroll
  for (int o = 32; o; o >>= 1) tot += __shfl_xor(tot, o, 64);
  if ((threadIdx.x & 63) == 0) atomicAdd(&conf[n], tot);
}

// ---------------- top-k + softmax; zeroes conf ----------------
__global__ void topk_k(float* __restrict__ conf, float* __restrict__ tkw,
                       int* __restrict__ tki) {
  if (threadIdx.x != 0) return;
  const float scale = 1.f / ((float)kHW * (float)kCorrDim);
  float c[kNS];
  for (int n = 0; n < kNS; ++n) c[n] = conf[n] * scale;
  int id[3] = {-1, -1, -1};
  float v[3];
  for (int k = 0; k < 3; ++k) {
    float best = -1e30f;
    int bi = -1;
    for (int n = 0; n < kNS; ++n) {
      if (n == id[0] || n == id[1] || n == id[2]) continue;
      if (c[n] > best) { best = c[n]; bi = n; }
    }
    v[k] = best;
    id[k] = bi;
  }
  float m = v[0];
  float e0 = expf(v[0] - m), e1 = expf(v[1] - m), e2 = expf(v[2] - m);
  float s = e0 + e1 + e2;
  tkw[0] = e0 / s; tkw[1] = e1 / s; tkw[2] = e2 / s;
  tki[0] = id[0]; tki[1] = id[1]; tki[2] = id[2];
  for (int n = 0; n < kNS; ++n) conf[n] = 0.f;
}

// ---------------- fused corr features via 10x10 windows -> bufT bf16 ----------------
__global__ __launch_bounds__(256) void fused_k(const unsigned short* __restrict__ corr0,
                                               const unsigned short* __restrict__ corr1,
                                               const unsigned short* __restrict__ corr2,
                                               const unsigned short* __restrict__ corr3,
                                               const float* __restrict__ X,
                                               const float* __restrict__ pose,
                                               const float* __restrict__ intr,
                                               const float* __restrict__ tkw,
                                               const int* __restrict__ tki,
                                               unsigned short* __restrict__ bufT) {
  __shared__ float win[12][10][12];
  __shared__ float s_fx[12], s_fy[12];
  __shared__ int   s_ix[12], s_iy[12];
  __shared__ float s_w[3];
  const int i = blockIdx.x;
  const int tid = threadIdx.x;

  if (tid < 3) {
    int n = tki[tid];
    s_w[tid] = tkw[tid];
    float S[12];
    sample_Rt(n, pose, S);
    float Xp[3] = {X[i*3], X[i*3+1], X[i*3+2]};
    float u, v;
    project_uv(S, Xp, intr, u, v);
#pragma unroll
    for (int l = 0; l < 4; ++l) {
      float s = (float)(1 << l);
      float bx = u / s, by = v / s;
      float fbx = floorf(bx), fby = floorf(by);
      s_ix[tid*4 + l] = (int)fbx;
      s_iy[tid*4 + l] = (int)fby;
      s_fx[tid*4 + l] = bx - fbx;
      s_fy[tid*4 + l] = by - fby;
    }
  }
  __syncthreads();

  // stage 12 clipped 10x10 windows, flattened over all 256 threads
  for (int sidx = tid; sidx < 1200; sidx += 256) {
    const int w = sidx / 100, rem = sidx % 100;
    const int rr = rem / 10, cc = rem % 10;
    const int lvl = w & 3;
    const int Wl = kW >> lvl, Hl = kH >> lvl;
    const unsigned short* base =
        (lvl == 0) ? corr0 : (lvl == 1) ? corr1 : (lvl == 2) ? corr2 : corr3;
    const int y = s_iy[w] - 4 + rr;
    const int x = s_ix[w] - 4 + cc;
    float v = 0.f;
    if (y >= 0 && y < Hl && x >= 0 && x < Wl)
      v = b2f(base[(size_t)i * (Hl * Wl) + y * Wl + x]);
    win[w][rr][cc] = v;
  }
  __syncthreads();

  for (int d = tid; d < kCorrDim; d += 256) {
    const int lvl = d / kP;
    const int o = d % kP;
    const int oyi = o / 9, oxi = o % 9;
    float val = 0.f;
#pragma unroll
    for (int k = 0; k < 3; ++k) {
      const int w = k * 4 + lvl;
      const float fx = s_fx[w], fy = s_fy[w];
      const float w00 = (1.f - fx) * (1.f - fy), w10 = fx * (1.f - fy);
      const float w01 = (1.f - fx) * fy, w11 = fx * fy;
      val += s_w[k] * (w00 * win[w][oyi][oxi] + w10 * win[w][oyi][oxi + 1] +
                       w01 * win[w][oyi + 1][oxi] + w11 * win[w][oyi + 1][oxi + 1]);
    }
    bufT[(size_t)i * kCinPad + kHidden + d] = f2b(val);
  }
}

// ---------------- LDS-free shifted-GEMM 3x3 conv core ----------------
template<int OC, int NCH, bool QMODE>
__device__ inline void conv_kloop(const unsigned short* __restrict__ inT,
                                  const unsigned short* __restrict__ rhT,
                                  const unsigned short* __restrict__ P,
                                  int y, int wv, int lane, int ocBlock,
                                  f32x4 (&acc)[2][2]) {
  const int m = lane & 15, kg = lane >> 4;
  const int ocW = ocBlock + (wv >> 1) * 32;
  const int pxW = (wv & 1) * 32;
#pragma unroll
  for (int tap = 0; tap < 9; ++tap) {
    const int dy = tap / 3 - 1, dx = tap % 3 - 1;
    const int yy = y + dy;
    if (yy < 0 || yy >= kH) continue;
    const int xs0 = pxW + m + dx, xs1 = pxW + 16 + m + dx;
    const bool v0 = (xs0 >= 0) && (xs0 < kW);
    const bool v1 = (xs1 >= 0) && (xs1 < kW);
    const int px0 = yy * kW + xs0, px1 = yy * kW + xs1;
    const unsigned short* a_base = P + ((size_t)(tap * NCH) * OC + ocW + m) * 32 + kg * 8;
#pragma unroll
    for (int cc = 0; cc < NCH; ++cc) {
      const unsigned short* srcB;
      int stride;
      if (QMODE && cc < 4) { srcB = rhT; stride = kHidden; }
      else                 { srcB = inT; stride = kCinPad; }
      short8 a0 = *(const short8*)(a_base + (size_t)cc * OC * 32);
      short8 a1 = *(const short8*)(a_base + (size_t)cc * OC * 32 + 16 * 32);
      short8 b0 = {0, 0, 0, 0, 0, 0, 0, 0};
      short8 b1 = {0, 0, 0, 0, 0, 0, 0, 0};
      if (v0) b0 = *(const short8*)(srcB + (size_t)px0 * stride + cc * 32 + kg * 8);
      if (v1) b1 = *(const short8*)(srcB + (size_t)px1 * stride + cc * 32 + kg * 8);
      acc[0][0] = __builtin_amdgcn_mfma_f32_16x16x32_bf16(a0, b0, acc[0][0], 0, 0, 0);
      acc[0][1] = __builtin_amdgcn_mfma_f32_16x16x32_bf16(a0, b1, acc[0][1], 0, 0, 0);
      acc[1][0] = __builtin_amdgcn_mfma_f32_16x16x32_bf16(a1, b0, acc[1][0], 0, 0, 0);
      acc[1][1] = __builtin_amdgcn_mfma_f32_16x16x32_bf16(a1, b1, acc[1][1], 0, 0, 0);
    }
  }
}

__global__ __launch_bounds__(256) void conv_zr_k(const unsigned short* __restrict__ bufT,
                                                 const unsigned short* __restrict__ P,
                                                 const float* __restrict__ bzr,
                                                 float* __restrict__ zpre,
                                                 const float* __restrict__ hbuf,
                                                 unsigned short* __restrict__ rhT) {
  const int tid = threadIdx.x;
  const int wv = tid >> 6, lane = tid & 63;
  const int y = blockIdx.y, ocBlock = blockIdx.x * 64;
  f32x4 acc[2][2] = {{{0.f,0.f,0.f,0.f},{0.f,0.f,0.f,0.f}},
                     {{0.f,0.f,0.f,0.f},{0.f,0.f,0.f,0.f}}};
  conv_kloop<256, 17, false>(bufT, nullptr, P, y, wv, lane, ocBlock, acc);
  const int m = lane & 15, kg = lane >> 4;
  const int ocW = ocBlock + (wv >> 1) * 32, pxW = (wv & 1) * 32;
#pragma unroll
  for (int ot = 0; ot < 2; ++ot)
#pragma unroll
    for (int t = 0; t < 2; ++t)
#pragma unroll
      for (int r = 0; r < 4; ++r) {
        const int oc = ocW + ot * 16 + kg * 4 + r;
        const int px = y * kW + pxW + t * 16 + m;
        const float val = acc[ot][t][r] + bzr[oc];
        if (oc < kHidden) {
          zpre[(size_t)oc * kHW + px] = val;
        } else {
          const float rg = 1.f / (1.f + expf(-val));
          rhT[(size_t)px * kHidden + oc - kHidden] = f2b(rg * hbuf[(size_t)(oc - kHidden) * kHW + px]);
        }
      }
}

__global__ __launch_bounds__(256) void conv_q_k(unsigned short* __restrict__ bufT,
                                                const unsigned short* __restrict__ rhT,
                                                const unsigned short* __restrict__ P,
                                                const float* __restrict__ bq,
                                                const float* __restrict__ zpre,
                                                float* __restrict__ hbuf) {
  const int tid = threadIdx.x;
  const int wv = tid >> 6, lane = tid & 63;
  const int y = blockIdx.y, ocBlock = blockIdx.x * 64;
  f32x4 acc[2][2] = {{{0.f,0.f,0.f,0.f},{0.f,0.f,0.f,0.f}},
                     {{0.f,0.f,0.f,0.f},{0.f,0.f,0.f,0.f}}};
  conv_kloop<128, 17, true>(bufT, rhT, P, y, wv, lane, ocBlock, acc);
  const int m = lane & 15, kg = lane >> 4;
  const int ocW = ocBlock + (wv >> 1) * 32, pxW = (wv & 1) * 32;
#pragma unroll
  for (int ot = 0; ot < 2; ++ot)
#pragma unroll
    for (int t = 0; t < 2; ++t)
#pragma unroll
      for (int r = 0; r < 4; ++r) {
        const int oc = ocW + ot * 16 + kg * 4 + r;
        const int px = y * kW + pxW + t * 16 + m;
        const size_t off = (size_t)oc * kHW + px;
        const float q = acc[ot][t][r] + bq[oc];
        const float zg = 1.f / (1.f + expf(-zpre[off]));
        const float hn = (1.f - zg) * hbuf[off] + zg * tanhf(q);
        hbuf[off] = hn;
        bufT[(size_t)px * kCinPad + oc] = f2b(hn);
      }
}

__global__ __launch_bounds__(256) void conv_h_k(const unsigned short* __restrict__ bufT,
                                                const unsigned short* __restrict__ P,
                                                const float* __restrict__ bh,
                                                float* __restrict__ feat) {
  __shared__ float fb[64];
  const int tid = threadIdx.x;
  const int wv = tid >> 6, lane = tid & 63;
  const int y = blockIdx.y, ocBlock = blockIdx.x * 64;
  f32x4 acc[2][2] = {{{0.f,0.f,0.f,0.f},{0.f,0.f,0.f,0.f}},
                     {{0.f,0.f,0.f,0.f},{0.f,0.f,0.f,0.f}}};
  conv_kloop<128, 4, false>(bufT, nullptr, P, y, wv, lane, ocBlock, acc);
  if (tid < 64) fb[tid] = 0.f;
  __syncthreads();
  const int m = lane & 15, kg = lane >> 4;
  const int ocW = ocBlock + (wv >> 1) * 32;
#pragma unroll
  for (int ot = 0; ot < 2; ++ot)
#pragma unroll
    for (int r = 0; r < 4; ++r) {
      const int oc = ocW + ot * 16 + kg * 4 + r;
      const float bv = bh[oc];
      float v = fmaxf(acc[ot][0][r] + bv, 0.f) + fmaxf(acc[ot][1][r] + bv, 0.f);
      v += __shfl_xor(v, 1, 64);
      v += __shfl_xor(v, 2, 64);
      v += __shfl_xor(v, 4, 64);
      v += __shfl_xor(v, 8, 64);
      if (m == 0) atomicAdd(&fb[oc - ocBlock], v);
    }
  __syncthreads();
  if (tid < 64) atomicAdd(&feat[ocBlock + tid], fb[tid]);
}

// ---------------- FC + pose update; zeroes feat ----------------
__global__ void pose_update_k(float* __restrict__ feat, const float* __restrict__ Wfc,
                              const float* __restrict__ bfc, float* __restrict__ pose,
                              float* __restrict__ out) {
  __shared__ float s_d[7];
  int t = threadIdx.x;
  if (t < 7) {
    float s = 0.f;
    const float inv = 1.f / (float)kHW;
    for (int k = 0; k < kHidden; ++k) s += (feat[k] * inv) * Wfc[k * 7 + t];
    s_d[t] = 0.01f * (s + bfc[t]);
  }
  __syncthreads();
  if (t < kHidden) feat[t] = 0.f;
  if (t != 0) return;
  float qc[4] = {pose[0], pose[1], pose[2], pose[3]};
  float tc[3] = {pose[4], pose[5], pose[6]};
  float dq[4] = {1.f + s_d[0], s_d[1], s_d[2], s_d[3]};
  float inv = 1.f / sqrtf(dq[0]*dq[0] + dq[1]*dq[1] + dq[2]*dq[2] + dq[3]*dq[3]);
  dq[0] *= inv; dq[1] *= inv; dq[2] *= inv; dq[3] *= inv;
  float dv[3] = {s_d[4], s_d[5], s_d[6]};
  float rv[3];
  d_qapply(qc, dv, rv);
  float tn[3] = {tc[0] + rv[0], tc[1] + rv[1], tc[2] + rv[2]};
  float qn[4];
  d_qmul(qc, dq, qn);
  float inv2 = 1.f / sqrtf(qn[0]*qn[0] + qn[1]*qn[1] + qn[2]*qn[2] + qn[3]*qn[3]);
  qn[0] *= inv2; qn[1] *= inv2; qn[2] *= inv2; qn[3] *= inv2;
  pose[0] = qn[0]; pose[1] = qn[1]; pose[2] = qn[2]; pose[3] = qn[3];
  pose[4] = tn[0]; pose[5] = tn[1]; pose[6] = tn[2];
  out[0] = qn[0]; out[1] = qn[1]; out[2] = qn[2]; out[3] = qn[3];
  out[4] = tn[0]; out[5] = tn[1]; out[6] = tn[2];
}

// ---------------- launch ----------------
extern "C" void kernel_launch(void* const* d_in, const int* in_sizes, int n_in,
                              void* d_out, int out_size, void* d_ws, size_t ws_size,
                              hipStream_t stream) {
  const float* frgb  = (const float*)d_in[0];
  const float* fdep  = (const float*)d_in[1];
  const float* depth = (const float*)d_in[2];
  const float* ctx   = (const float*)d_in[3];
  const float* intr  = (const float*)d_in[4];
  const float* Wz = (const float*)d_in[5];
  const float* bz = (const float*)d_in[6];
  const float* Wr = (const float*)d_in[7];
  const float* br = (const float*)d_in[8];
  const float* Wq = (const float*)d_in[9];
  const float* bq = (const float*)d_in[10];
  const float* Wh = (const float*)d_in[11];
  const float* bh = (const float*)d_in[12];
  const float* Wfc = (const float*)d_in[13];
  const float* bfc = (const float*)d_in[14];
  float* outp = (float*)d_out;

  float* ws = (float*)d_ws;
  unsigned short* us = (unsigned short*)d_ws;
  unsigned short* corr0 = us + U_CORR0;
  unsigned short* corr1 = us + U_CORR1;
  unsigned short* corr2 = us + U_CORR2;
  unsigned short* corr3 = us + U_CORR3;
  float* X    = ws + F_X;
  float* hbuf = ws + F_H;
  float* zpre = ws + F_ZPRE;
  unsigned short* bufT = us + U_BUFT;
  unsigned short* rhT  = us + U_RHT;
  unsigned short* Pzr  = us + U_PZR;
  unsigned short* Pq   = us + U_PQ;
  unsigned short* Ph   = us + U_PH;
  float* bzr  = ws + F_BZR;
  float* conf = ws + F_CONF;
  float* tkw  = ws + F_TK;
  int*   tki  = (int*)(ws + F_TK + 3);
  float* pose = ws + F_POSE;
  float* feat = ws + F_FEAT;
  unsigned short* fdT  = us + U_FDT;
  unsigned short* qT   = us + U_QT;
  unsigned short* Sbox = us + U_SBOX;  // overlays fdT/qT after setup

  init_k<<<1536, 256, 0, stream>>>(ctx, bz, br, depth, intr, hbuf, bufT, bzr, X,
                                   conf, feat, pose);
  pack_k<<<(kStepsBig * 256 * 4 + 255) / 256, 256, 0, stream>>>(Wz, Wr, 128, 256,
                                                                kStepsBig, 17, kGin, Pzr);
  pack_k<<<(kStepsBig * 128 * 4 + 255) / 256, 256, 0, stream>>>(Wq, Wq, 128, 128,
                                                                kStepsBig, 17, kGin, Pq);
  pack_k<<<(kStepsH * 128 * 4 + 255) / 256, 256, 0, stream>>>(Wh, Wh, 128, 128,
                                                              kStepsH, 4, kHidden, Ph);
  t_bf16_k<<<dim3(48, 4), 256, 0, stream>>>(fdep, fdT);
  t_bf16_k<<<dim3(48, 4), 256, 0, stream>>>(frgb, qT);
  corr_mfma_k<<<dim3(24, 24), 256, 0, stream>>>(fdT, qT, corr0);
  {
    int t1 = kHW * 24 * 32, t2 = kHW * 12 * 16, t3 = kHW * 6 * 8;
    pool2_k<<<(t1 + 255) / 256, 256, 0, stream>>>(corr0, corr1, 48, 64);
    pool2_k<<<(t2 + 255) / 256, 256, 0, stream>>>(corr1, corr2, 24, 32);
    pool2_k<<<(t3 + 255) / 256, 256, 0, stream>>>(corr2, corr3, 12, 16);
  }
  // build box-filtered pyramid (fdT/qT are dead from here on)
  boxh_k<<<1080, 256, 0, stream>>>(corr0, corr1, corr2, corr3, Sbox);
  boxv_k<<<1920, 256, 0, stream>>>(Sbox);

  for (int it = 0; it < kIters; ++it) {
    conf_k<<<444, 256, 0, stream>>>(Sbox, X, pose, intr, conf);
    topk_k<<<1, 64, 0, stream>>>(conf, tkw, tki);
    fused_k<<<kHW, 256, 0, stream>>>(corr0, corr1, corr2, corr3, X, pose, intr,
                                     tkw, tki, bufT);
    conv_zr_k<<<dim3(4, 48), 256, 0, stream>>>(bufT, Pzr, bzr, zpre, hbuf, rhT);
    conv_q_k<<<dim3(2, 48), 256, 0, stream>>>(bufT, rhT, Pq, bq, zpre, hbuf);
    conv_h_k<<<dim3(2, 48), 256, 0, stream>>>(bufT, Ph, bh, feat);
    pose_update_k<<<1, 128, 0, stream>>>(feat, Wfc, bfc, pose, outp);
  }
}

// Round 6
// 903.979 us; speedup vs baseline: 1.3131x; 1.3131x over previous
//
#include <hip/hip_runtime.h>
#include <math.h>

// ---------------- problem constants ----------------
constexpr int kH = 48, kW = 64, kHW = 3072, kC = 256;
constexpr int kHidden = 128, kCtx = 64;
constexpr int kP = 81, kCorrDim = 324;  // 81*4
constexpr int kNS = 37, kIters = 4;
constexpr int kGin = kHidden + kCorrDim + kCtx;  // 516
constexpr int kCinPad = 544;                     // 17*32
constexpr int kStepsBig = 17 * 9;                // 153
constexpr int kStepsH = 4 * 9;                   // 36

// box-filtered pyramid (padded +10 each dim), per source pixel:
// L0 74x58, L1 42x34, L2 26x22, L3 18x16 -> 6580 entries
constexpr int kSB0 = 0, kSB1 = 4292, kSB2 = 5720, kSB3 = 6292, kSBTot = 6580;
// horizontal-pass buffer (padded cols, unpadded rows): 74x48, 42x24, 26x12, 18x6
constexpr int kHB0 = 0, kHB1 = 3552, kHB2 = 4560, kHB3 = 4872, kHBTot = 4980;

// ---------------- workspace layout ----------------
// ushort-unit offsets
constexpr size_t U_CORR0 = 0;                                   // 3072*3072
constexpr size_t U_CORR1 = U_CORR0 + (size_t)kHW * 3072;        // 3072*768
constexpr size_t U_CORR2 = U_CORR1 + (size_t)kHW * 768;         // 3072*192
constexpr size_t U_CORR3 = U_CORR2 + (size_t)kHW * 192;         // 3072*48
constexpr size_t U_END0  = U_CORR3 + (size_t)kHW * 48;          // 12533760
// float-unit offsets
constexpr size_t F_X     = U_END0 / 2;                          // 3072*3
constexpr size_t F_H     = F_X + (size_t)kHW * 3;               // 128*3072
constexpr size_t F_ZPRE  = F_H + (size_t)kHidden * kHW;         // 128*3072
constexpr size_t F_END1  = F_ZPRE + (size_t)kHidden * kHW;
// ushort buffers
constexpr size_t U_BUFT  = F_END1 * 2;                          // 3072*544
constexpr size_t U_RHT   = U_BUFT + (size_t)kHW * kCinPad;      // 3072*128
constexpr size_t U_PZR   = U_RHT + (size_t)kHW * kHidden;       // 153*256*32
constexpr size_t U_PQ    = U_PZR + (size_t)kStepsBig * 256 * 32;
constexpr size_t U_PH    = U_PQ + (size_t)kStepsBig * 128 * 32;
constexpr size_t U_END2  = U_PH + (size_t)kStepsH * 128 * 32;
// small float scalars
constexpr size_t F_BZR   = (U_END2 + 2) / 2;  // 256
constexpr size_t F_CONF  = F_BZR + 256;       // 64
constexpr size_t F_TK    = F_CONF + 64;       // 16
constexpr size_t F_POSE  = F_TK + 16;         // 16
constexpr size_t F_FEAT  = F_POSE + 16;       // 128
constexpr size_t F_END3  = F_FEAT + 128;
// transposed bf16 feature maps (setup-only) -- Sbox overlays them afterwards
constexpr size_t U_FDT   = F_END3 * 2;                   // 3072*256
constexpr size_t U_QT    = U_FDT + (size_t)kHW * kC;     // 3072*256
constexpr size_t U_SBOX  = U_FDT;                        // 3072*6580 (reuses fdT/qT)

typedef __attribute__((ext_vector_type(8))) short short8;
typedef __attribute__((ext_vector_type(4))) float f32x4;

__device__ inline unsigned short f2b(float f) {
  unsigned int u = __float_as_uint(f);
  unsigned int r = u + 0x7FFF + ((u >> 16) & 1);
  return (unsigned short)(r >> 16);
}
__device__ inline float b2f(unsigned short u) {
  return __uint_as_float(((unsigned int)u) << 16);
}
__device__ inline int clampi(int v, int lo, int hi) { return min(max(v, lo), hi); }

// ---------------- sample templates ----------------
__constant__ float c_rot[12][3] = {
  {0,0,0},{0,0,0},{0,0,0},{0,0,0},{0,0,0},{0,0,0},
  {1,0,0},{-1,0,0},{0,1,0},{0,-1,0},{0,0,1},{0,0,-1}};
__constant__ float c_trs[12][3] = {
  {1,0,0},{-1,0,0},{0,1,0},{0,-1,0},{0,0,1},{0,0,-1},
  {0,0,0},{0,0,0},{0,0,0},{0,0,0},{0,0,0},{0,0,0}};

// ---------------- device helpers ----------------
__device__ inline void d_qmul(const float* q, const float* r, float* o) {
  o[0] = q[0]*r[0] - q[1]*r[1] - q[2]*r[2] - q[3]*r[3];
  o[1] = q[0]*r[1] + q[1]*r[0] + q[2]*r[3] - q[3]*r[2];
  o[2] = q[0]*r[2] - q[1]*r[3] + q[2]*r[0] + q[3]*r[1];
  o[3] = q[0]*r[3] + q[1]*r[2] - q[2]*r[1] + q[3]*r[0];
}
__device__ inline void d_qapply(const float* q, const float* v, float* o) {
  float a0 = -q[1]*v[0] - q[2]*v[1] - q[3]*v[2];
  float a1 =  q[0]*v[0] + q[2]*v[2] - q[3]*v[1];
  float a2 =  q[0]*v[1] - q[1]*v[2] + q[3]*v[0];
  float a3 =  q[0]*v[2] + q[1]*v[1] - q[2]*v[0];
  o[0] = -a0*q[1] + a1*q[0] - a2*q[3] + a3*q[2];
  o[1] = -a0*q[2] + a1*q[3] + a2*q[0] - a3*q[1];
  o[2] = -a0*q[3] - a1*q[2] + a2*q[1] + a3*q[0];
}
__device__ inline void d_intr(const float* intr, float& fx, float& fy, float& cx, float& cy) {
  fx = 60.f + 40.f*intr[0];
  fy = 60.f + 40.f*intr[1];
  cx = 32.f + 4.f*(intr[2] - 0.5f);
  cy = 24.f + 4.f*(intr[3] - 0.5f);
}
__device__ inline void sample_Rt(int t, const float* __restrict__ pose, float* S) {
  float qc[4] = {pose[0], pose[1], pose[2], pose[3]};
  float tc[3] = {pose[4], pose[5], pose[6]};
  float dq[4], dt[3];
  if (t == 36) {
    dq[0] = 1.f; dq[1] = dq[2] = dq[3] = 0.f;
    dt[0] = dt[1] = dt[2] = 0.f;
  } else {
    int j = t / 3, k = t % 3;
    float sc = (k == 0) ? 0.25f : ((k == 1) ? 1.f : 4.f);
    float rx = c_rot[j][0], ry = c_rot[j][1], rz = c_rot[j][2];
    float nrm = sqrtf(rx*rx + ry*ry + rz*rz);
    float axn = fmaxf(nrm, 1e-8f);
    float ax = rx / axn, ay = ry / axn, az = rz / axn;
    float ha = 0.02f * sc * 0.5f;
    float sh = sinf(ha), ch = cosf(ha);
    dq[0] = ch; dq[1] = ax * sh; dq[2] = ay * sh; dq[3] = az * sh;
    dt[0] = c_trs[j][0] * (0.02f * sc);
    dt[1] = c_trs[j][1] * (0.02f * sc);
    dt[2] = c_trs[j][2] * (0.02f * sc);
  }
  float qn[4];
  d_qmul(qc, dq, qn);
  float inv = 1.f / sqrtf(qn[0]*qn[0] + qn[1]*qn[1] + qn[2]*qn[2] + qn[3]*qn[3]);
  qn[0] *= inv; qn[1] *= inv; qn[2] *= inv; qn[3] *= inv;
  float tr[3];
  d_qapply(qc, dt, tr);
  float w = qn[0], x = qn[1], y = qn[2], z = qn[3];
  S[0] = 1.f - 2.f*(y*y + z*z); S[1] = 2.f*(x*y - w*z);       S[2] = 2.f*(x*z + w*y);
  S[3] = 2.f*(x*y + w*z);       S[4] = 1.f - 2.f*(x*x + z*z); S[5] = 2.f*(y*z - w*x);
  S[6] = 2.f*(x*z - w*y);       S[7] = 2.f*(y*z + w*x);       S[8] = 1.f - 2.f*(x*x + y*y);
  S[9]  = tc[0] + tr[0];
  S[10] = tc[1] + tr[1];
  S[11] = tc[2] + tr[2];
}
__device__ inline void project_uv(const float* S, const float* Xp, const float* intr,
                                  float& u, float& v) {
  float xc0 = S[0]*Xp[0] + S[1]*Xp[1] + S[2]*Xp[2] + S[9];
  float xc1 = S[3]*Xp[0] + S[4]*Xp[1] + S[5]*Xp[2] + S[10];
  float xc2 = S[6]*Xp[0] + S[7]*Xp[1] + S[8]*Xp[2] + S[11];
  float z = fmaxf(xc2, 0.1f);
  float fx, fy, cx, cy;
  d_intr(intr, fx, fy, cx, cy);
  u = fx * xc0 / z + cx;
  v = fy * xc1 / z + cy;
}

// ---------------- init ----------------
__global__ void init_k(const float* __restrict__ ctx, const float* __restrict__ bz,
                       const float* __restrict__ br, const float* __restrict__ depth,
                       const float* __restrict__ intr, float* __restrict__ h,
                       unsigned short* __restrict__ bufT, float* __restrict__ bzr,
                       float* __restrict__ X, float* __restrict__ conf,
                       float* __restrict__ feat, float* __restrict__ pose) {
  int idx = blockIdx.x * blockDim.x + threadIdx.x;
  if (idx < kHidden * kHW) {
    h[idx] = 0.f;
    int p = idx >> 7, c = idx & 127;
    bufT[(size_t)p * kCinPad + c] = 0;
  }
  if (idx < kHW * 92) {  // ctx cols 452..515 + zero pad 516..543
    int p = idx / 92, c = idx % 92;
    unsigned short v = 0;
    if (c < 64) v = f2b(ctx[(size_t)c * kHW + p]);
    bufT[(size_t)p * kCinPad + 452 + c] = v;
  }
  if (idx < kHW) {
    float fx, fy, cx, cy;
    d_intr(intr, fx, fy, cx, cy);
    float d = 4.f + 20.f * depth[idx];
    float u = (float)(idx % kW), v = (float)(idx / kW);
    X[idx*3+0] = (u - cx) / fx * d;
    X[idx*3+1] = (v - cy) / fy * d;
    X[idx*3+2] = d;
  }
  if (idx < 256) bzr[idx] = (idx < 128) ? bz[idx] : br[idx - 128];
  if (idx < 64) conf[idx] = 0.f;
  if (idx < 128) feat[idx] = 0.f;
  if (idx == 0) {
    pose[0] = 1.f;
    for (int j = 1; j < 7; ++j) pose[j] = 0.f;
  }
}

// ---------------- weight prepack (tap-major) ----------------
__global__ void pack_k(const float* __restrict__ W0, const float* __restrict__ W1,
                       int ocSplit, int OC, int nsteps, int nchunks, int Cin,
                       unsigned short* __restrict__ P) {
  int idx = blockIdx.x * blockDim.x + threadIdx.x;
  int total = nsteps * OC * 4;
  if (idx >= total) return;
  int g = idx & 3;
  int oc = (idx >> 2) % OC;
  int s = idx / (OC * 4);
  int tap = s / nchunks, cc = s % nchunks;
  union { unsigned short u[8]; uint4 q; } v;
#pragma unroll
  for (int j = 0; j < 8; ++j) {
    int ci = cc * 32 + g * 8 + j;
    float w = 0.f;
    if (ci < Cin)
      w = (oc < ocSplit) ? W0[((size_t)oc * Cin + ci) * 9 + tap]
                         : W1[((size_t)(oc - ocSplit) * Cin + ci) * 9 + tap];
    v.u[j] = f2b(w);
  }
  *(uint4*)&P[(size_t)idx * 8] = v.q;
}

// ---------------- fp32 [C][HW] -> bf16 [HW][C] transpose ----------------
__global__ __launch_bounds__(256) void t_bf16_k(const float* __restrict__ src,
                                                unsigned short* __restrict__ dst) {
  __shared__ float t[64][65];
  const int tid = threadIdx.x;
  const int p0 = blockIdx.x * 64, c0 = blockIdx.y * 64;
  const int tx = tid & 63, ty = tid >> 6;
  for (int cl = ty; cl < 64; cl += 4)
    t[cl][tx] = src[(size_t)(c0 + cl) * kHW + p0 + tx];
  __syncthreads();
  for (int pl = ty; pl < 64; pl += 4)
    dst[(size_t)(p0 + pl) * kC + c0 + tx] = f2b(t[tx][pl]);
}

// ---------------- corr GEMM via MFMA -> bf16 pyramid L0 ----------------
__global__ __launch_bounds__(256) void corr_mfma_k(const unsigned short* __restrict__ fdT,
                                                   const unsigned short* __restrict__ qT,
                                                   unsigned short* __restrict__ Cg) {
  const int tid = threadIdx.x;
  const int wv = tid >> 6, lane = tid & 63;
  const int m = lane & 15, kg = lane >> 4;
  const int i0 = blockIdx.y * 128 + wv * 32;
  const int q0 = blockIdx.x * 128;

  f32x4 acc[2][8];
#pragma unroll
  for (int t = 0; t < 2; ++t)
#pragma unroll
    for (int u = 0; u < 8; ++u) acc[t][u] = (f32x4){0.f, 0.f, 0.f, 0.f};

#pragma unroll
  for (int kc = 0; kc < 8; ++kc) {
    const int kb = kc * 32 + kg * 8;
    short8 a[2], b[8];
#pragma unroll
    for (int t = 0; t < 2; ++t)
      a[t] = *(const short8*)&fdT[(size_t)(i0 + t * 16 + m) * kC + kb];
#pragma unroll
    for (int u = 0; u < 8; ++u)
      b[u] = *(const short8*)&qT[(size_t)(q0 + u * 16 + m) * kC + kb];
#pragma unroll
    for (int t = 0; t < 2; ++t)
#pragma unroll
      for (int u = 0; u < 8; ++u)
        acc[t][u] = __builtin_amdgcn_mfma_f32_16x16x32_bf16(a[t], b[u], acc[t][u], 0, 0, 0);
  }
  const float S = 0.0625f;
#pragma unroll
  for (int t = 0; t < 2; ++t)
#pragma unroll
    for (int u = 0; u < 8; ++u)
#pragma unroll
      for (int r = 0; r < 4; ++r)
        Cg[(size_t)(i0 + t * 16 + kg * 4 + r) * kHW + q0 + u * 16 + m] = f2b(acc[t][u][r] * S);
}

// ---------------- 2x2 avg pool (bf16) ----------------
__global__ void pool2_k(const unsigned short* __restrict__ in,
                        unsigned short* __restrict__ out, int Hi, int Wi) {
  int Ho = Hi / 2, Wo = Wi / 2;
  int total = kHW * Ho * Wo;
  int idx = blockIdx.x * blockDim.x + threadIdx.x;
  if (idx >= total) return;
  int i = idx / (Ho * Wo);
  int r = idx % (Ho * Wo);
  int y = r / Wo, x = r % Wo;
  const unsigned short* p = in + (size_t)i * Hi * Wi;
  float v = 0.25f * (b2f(p[(2*y)*Wi + 2*x]) + b2f(p[(2*y)*Wi + 2*x + 1]) +
                     b2f(p[(2*y+1)*Wi + 2*x]) + b2f(p[(2*y+1)*Wi + 2*x + 1]));
  out[idx] = f2b(v);
}

// ---------------- box-filter build: one block per source pixel, all in LDS ----------------
// Sbox cell (as,bp,l): S = sum_{r=bp-9..bp-1} H(as,r), H(as,y) = sum_{x=as-9..as-1} P(x,y)
// (as,bp are padded coords; P zero outside [0,Wl)x[0,Hl))
__global__ __launch_bounds__(256) void boxbuild_k(const unsigned short* __restrict__ corr0,
                                                  const unsigned short* __restrict__ corr1,
                                                  const unsigned short* __restrict__ corr2,
                                                  const unsigned short* __restrict__ corr3,
                                                  unsigned short* __restrict__ Sbox) {
  __shared__ float pyr[4080];
  __shared__ float hb[kHBTot];
  const int i = blockIdx.x;
  const int tid = threadIdx.x;

  // stage pyramid row (coalesced)
  for (int idx = tid; idx < 4080; idx += 256) {
    float v;
    if (idx < 3072)      v = b2f(corr0[(size_t)i * 3072 + idx]);
    else if (idx < 3840) v = b2f(corr1[(size_t)i * 768 + idx - 3072]);
    else if (idx < 4032) v = b2f(corr2[(size_t)i * 192 + idx - 3840]);
    else                 v = b2f(corr3[(size_t)i * 48 + idx - 4032]);
    pyr[idx] = v;
  }
  __syncthreads();

  const int lvl_off[4] = {0, 3072, 3840, 4032};
  // horizontal 9-tap pass -> hb (padded cols, unpadded rows)
  for (int c = tid; c < kHBTot; c += 256) {
    int lvl, rem;
    if (c < kHB1)      { lvl = 0; rem = c; }
    else if (c < kHB2) { lvl = 1; rem = c - kHB1; }
    else if (c < kHB3) { lvl = 2; rem = c - kHB2; }
    else               { lvl = 3; rem = c - kHB3; }
    const int Wl = kW >> lvl, Wp = Wl + 10;
    const int y = rem / Wp, as = rem % Wp;
    const float* row = &pyr[lvl_off[lvl] + y * Wl];
    const int x0 = max(0, as - 9), x1 = min(Wl - 1, as - 1);
    float s = 0.f;
    for (int x = x0; x <= x1; ++x) s += row[x];
    hb[c] = s;
  }
  __syncthreads();

  // vertical 9-tap pass -> Sbox (coalesced global write)
  const int hoff[4] = {kHB0, kHB1, kHB2, kHB3};
  unsigned short* out = Sbox + (size_t)i * kSBTot;
  for (int c = tid; c < kSBTot; c += 256) {
    int lvl, rem;
    if (c < kSB1)      { lvl = 0; rem = c; }
    else if (c < kSB2) { lvl = 1; rem = c - kSB1; }
    else if (c < kSB3) { lvl = 2; rem = c - kSB2; }
    else               { lvl = 3; rem = c - kSB3; }
    const int Wl = kW >> lvl, Hl = kH >> lvl, Wp = Wl + 10;
    const int bp = rem / Wp, as = rem % Wp;
    const float* col = &hb[hoff[lvl] + as];
    const int r0 = max(0, bp - 9), r1 = min(Hl - 1, bp - 1);
    float s = 0.f;
    for (int r = r0; r <= r1; ++r) s += col[r * Wp];
    out[c] = f2b(s);
  }
}

// ---------------- conf: one thread per (sample, pixel); 16 Sbox reads ----------------
__global__ __launch_bounds__(256) void conf_k(const unsigned short* __restrict__ Sbox,
                                              const float* __restrict__ X,
                                              const float* __restrict__ pose,
                                              const float* __restrict__ intr,
                                              float* __restrict__ conf) {
  const int idx = blockIdx.x * 256 + threadIdx.x;  // n*3072 + i
  const int n = idx / kHW, i = idx - n * kHW;
  float S[12];
  sample_Rt(n, pose, S);
  float Xp[3] = {X[i*3], X[i*3+1], X[i*3+2]};
  float u, v;
  project_uv(S, Xp, intr, u, v);
  const unsigned short* sb = Sbox + (size_t)i * kSBTot;
  float tot = 0.f;
#pragma unroll
  for (int l = 0; l < 4; ++l) {
    const int Wp = (kW >> l) + 10, Hp = (kH >> l) + 10;
    const int so = (l == 0) ? kSB0 : (l == 1) ? kSB1 : (l == 2) ? kSB2 : kSB3;
    const float s = (float)(1 << l);
    const float bx = u / s, by = v / s;
    const float fbx = floorf(bx), fby = floorf(by);
    const int x0 = (int)fbx, y0 = (int)fby;
    const float fx = bx - fbx, fy = by - fby;
    const int xa = clampi(x0 + 5, 0, Wp - 1), xb = clampi(x0 + 6, 0, Wp - 1);
    const int ya = clampi(y0 + 5, 0, Hp - 1), yb = clampi(y0 + 6, 0, Hp - 1);
    const float s00 = b2f(sb[so + ya * Wp + xa]), s10 = b2f(sb[so + ya * Wp + xb]);
    const float s01 = b2f(sb[so + yb * Wp + xa]), s11 = b2f(sb[so + yb * Wp + xb]);
    tot += (1.f - fx) * (1.f - fy) * s00 + fx * (1.f - fy) * s10 +
           (1.f - fx) * fy * s01 + fx * fy * s11;
  }
#pragma unroll
  for (int o = 32; o; o >>= 1) tot += __shfl_xor(tot, o, 64);
  if ((threadIdx.x & 63) == 0) atomicAdd(&conf[n], tot);
}

// ---------------- top-k + softmax; zeroes conf ----------------
__global__ void topk_k(float* __restrict__ conf, float* __restrict__ tkw,
                       int* __restrict__ tki) {
  if (threadIdx.x != 0) return;
  const float scale = 1.f / ((float)kHW * (float)kCorrDim);
  float c[kNS];
  for (int n = 0; n < kNS; ++n) c[n] = conf[n] * scale;
  int id[3] = {-1, -1, -1};
  float v[3];
  for (int k = 0; k < 3; ++k) {
    float best = -1e30f;
    int bi = -1;
    for (int n = 0; n < kNS; ++n) {
      if (n == id[0] || n == id[1] || n == id[2]) continue;
      if (c[n] > best) { best = c[n]; bi = n; }
    }
    v[k] = best;
    id[k] = bi;
  }
  float m = v[0];
  float e0 = expf(v[0] - m), e1 = expf(v[1] - m), e2 = expf(v[2] - m);
  float s = e0 + e1 + e2;
  tkw[0] = e0 / s; tkw[1] = e1 / s; tkw[2] = e2 / s;
  tki[0] = id[0]; tki[1] = id[1]; tki[2] = id[2];
  for (int n = 0; n < kNS; ++n) conf[n] = 0.f;
}

// ---------------- fused corr features via 10x10 windows -> bufT bf16 ----------------
__global__ __launch_bounds__(256) void fused_k(const unsigned short* __restrict__ corr0,
                                               const unsigned short* __restrict__ corr1,
                                               const unsigned short* __restrict__ corr2,
                                               const unsigned short* __restrict__ corr3,
                                               const float* __restrict__ X,
                                               const float* __restrict__ pose,
                                               const float* __restrict__ intr,
                                               const float* __restrict__ tkw,
                                               const int* __restrict__ tki,
                                               unsigned short* __restrict__ bufT) {
  __shared__ float win[12][10][12];
  __shared__ float s_fx[12], s_fy[12];
  __shared__ int   s_ix[12], s_iy[12];
  __shared__ float s_w[3];
  const int i = blockIdx.x;
  const int tid = threadIdx.x;

  if (tid < 3) {
    int n = tki[tid];
    s_w[tid] = tkw[tid];
    float S[12];
    sample_Rt(n, pose, S);
    float Xp[3] = {X[i*3], X[i*3+1], X[i*3+2]};
    float u, v;
    project_uv(S, Xp, intr, u, v);
#pragma unroll
    for (int l = 0; l < 4; ++l) {
      float s = (float)(1 << l);
      float bx = u / s, by = v / s;
      float fbx = floorf(bx), fby = floorf(by);
      s_ix[tid*4 + l] = (int)fbx;
      s_iy[tid*4 + l] = (int)fby;
      s_fx[tid*4 + l] = bx - fbx;
      s_fy[tid*4 + l] = by - fby;
    }
  }
  __syncthreads();

  for (int sidx = tid; sidx < 1200; sidx += 256) {
    const int w = sidx / 100, rem = sidx % 100;
    const int rr = rem / 10, cc = rem % 10;
    const int lvl = w & 3;
    const int Wl = kW >> lvl, Hl = kH >> lvl;
    const unsigned short* base =
        (lvl == 0) ? corr0 : (lvl == 1) ? corr1 : (lvl == 2) ? corr2 : corr3;
    const int y = s_iy[w] - 4 + rr;
    const int x = s_ix[w] - 4 + cc;
    float v = 0.f;
    if (y >= 0 && y < Hl && x >= 0 && x < Wl)
      v = b2f(base[(size_t)i * (Hl * Wl) + y * Wl + x]);
    win[w][rr][cc] = v;
  }
  __syncthreads();

  for (int d = tid; d < kCorrDim; d += 256) {
    const int lvl = d / kP;
    const int o = d % kP;
    const int oyi = o / 9, oxi = o % 9;
    float val = 0.f;
#pragma unroll
    for (int k = 0; k < 3; ++k) {
      const int w = k * 4 + lvl;
      const float fx = s_fx[w], fy = s_fy[w];
      const float w00 = (1.f - fx) * (1.f - fy), w10 = fx * (1.f - fy);
      const float w01 = (1.f - fx) * fy, w11 = fx * fy;
      val += s_w[k] * (w00 * win[w][oyi][oxi] + w10 * win[w][oyi][oxi + 1] +
                       w01 * win[w][oyi + 1][oxi] + w11 * win[w][oyi + 1][oxi + 1]);
    }
    bufT[(size_t)i * kCinPad + kHidden + d] = f2b(val);
  }
}

// ---------------- LDS-free shifted-GEMM 3x3 conv core ----------------
template<int OC, int NCH, bool QMODE>
__device__ inline void conv_kloop(const unsigned short* __restrict__ inT,
                                  const unsigned short* __restrict__ rhT,
                                  const unsigned short* __restrict__ P,
                                  int y, int wv, int lane, int ocBlock,
                                  f32x4 (&acc)[2][2]) {
  const int m = lane & 15, kg = lane >> 4;
  const int ocW = ocBlock + (wv >> 1) * 32;
  const int pxW = (wv & 1) * 32;
#pragma unroll
  for (int tap = 0; tap < 9; ++tap) {
    const int dy = tap / 3 - 1, dx = tap % 3 - 1;
    const int yy = y + dy;
    if (yy < 0 || yy >= kH) continue;
    const int xs0 = pxW + m + dx, xs1 = pxW + 16 + m + dx;
    const bool v0 = (xs0 >= 0) && (xs0 < kW);
    const bool v1 = (xs1 >= 0) && (xs1 < kW);
    const int px0 = yy * kW + xs0, px1 = yy * kW + xs1;
    const unsigned short* a_base = P + ((size_t)(tap * NCH) * OC + ocW + m) * 32 + kg * 8;
#pragma unroll
    for (int cc = 0; cc < NCH; ++cc) {
      const unsigned short* srcB;
      int stride;
      if (QMODE && cc < 4) { srcB = rhT; stride = kHidden; }
      else                 { srcB = inT; stride = kCinPad; }
      short8 a0 = *(const short8*)(a_base + (size_t)cc * OC * 32);
      short8 a1 = *(const short8*)(a_base + (size_t)cc * OC * 32 + 16 * 32);
      short8 b0 = {0, 0, 0, 0, 0, 0, 0, 0};
      short8 b1 = {0, 0, 0, 0, 0, 0, 0, 0};
      if (v0) b0 = *(const short8*)(srcB + (size_t)px0 * stride + cc * 32 + kg * 8);
      if (v1) b1 = *(const short8*)(srcB + (size_t)px1 * stride + cc * 32 + kg * 8);
      acc[0][0] = __builtin_amdgcn_mfma_f32_16x16x32_bf16(a0, b0, acc[0][0], 0, 0, 0);
      acc[0][1] = __builtin_amdgcn_mfma_f32_16x16x32_bf16(a0, b1, acc[0][1], 0, 0, 0);
      acc[1][0] = __builtin_amdgcn_mfma_f32_16x16x32_bf16(a1, b0, acc[1][0], 0, 0, 0);
      acc[1][1] = __builtin_amdgcn_mfma_f32_16x16x32_bf16(a1, b1, acc[1][1], 0, 0, 0);
    }
  }
}

__global__ __launch_bounds__(256) void conv_zr_k(const unsigned short* __restrict__ bufT,
                                                 const unsigned short* __restrict__ P,
                                                 const float* __restrict__ bzr,
                                                 float* __restrict__ zpre,
                                                 const float* __restrict__ hbuf,
                                                 unsigned short* __restrict__ rhT) {
  const int tid = threadIdx.x;
  const int wv = tid >> 6, lane = tid & 63;
  const int y = blockIdx.y, ocBlock = blockIdx.x * 64;
  f32x4 acc[2][2] = {{{0.f,0.f,0.f,0.f},{0.f,0.f,0.f,0.f}},
                     {{0.f,0.f,0.f,0.f},{0.f,0.f,0.f,0.f}}};
  conv_kloop<256, 17, false>(bufT, nullptr, P, y, wv, lane, ocBlock, acc);
  const int m = lane & 15, kg = lane >> 4;
  const int ocW = ocBlock + (wv >> 1) * 32, pxW = (wv & 1) * 32;
#pragma unroll
  for (int ot = 0; ot < 2; ++ot)
#pragma unroll
    for (int t = 0; t < 2; ++t)
#pragma unroll
      for (int r = 0; r < 4; ++r) {
        const int oc = ocW + ot * 16 + kg * 4 + r;
        const int px = y * kW + pxW + t * 16 + m;
        const float val = acc[ot][t][r] + bzr[oc];
        if (oc < kHidden) {
          zpre[(size_t)oc * kHW + px] = val;
        } else {
          const float rg = 1.f / (1.f + expf(-val));
          rhT[(size_t)px * kHidden + oc - kHidden] = f2b(rg * hbuf[(size_t)(oc - kHidden) * kHW + px]);
        }
      }
}

__global__ __launch_bounds__(256) void conv_q_k(unsigned short* __restrict__ bufT,
                                                const unsigned short* __restrict__ rhT,
                                                const unsigned short* __restrict__ P,
                                                const float* __restrict__ bq,
                                                const float* __restrict__ zpre,
                                                float* __restrict__ hbuf) {
  const int tid = threadIdx.x;
  const int wv = tid >> 6, lane = tid & 63;
  const int y = blockIdx.y, ocBlock = blockIdx.x * 64;
  f32x4 acc[2][2] = {{{0.f,0.f,0.f,0.f},{0.f,0.f,0.f,0.f}},
                     {{0.f,0.f,0.f,0.f},{0.f,0.f,0.f,0.f}}};
  conv_kloop<128, 17, true>(bufT, rhT, P, y, wv, lane, ocBlock, acc);
  const int m = lane & 15, kg = lane >> 4;
  const int ocW = ocBlock + (wv >> 1) * 32, pxW = (wv & 1) * 32;
#pragma unroll
  for (int ot = 0; ot < 2; ++ot)
#pragma unroll
    for (int t = 0; t < 2; ++t)
#pragma unroll
      for (int r = 0; r < 4; ++r) {
        const int oc = ocW + ot * 16 + kg * 4 + r;
        const int px = y * kW + pxW + t * 16 + m;
        const size_t off = (size_t)oc * kHW + px;
        const float q = acc[ot][t][r] + bq[oc];
        const float zg = 1.f / (1.f + expf(-zpre[off]));
        const float hn = (1.f - zg) * hbuf[off] + zg * tanhf(q);
        hbuf[off] = hn;
        bufT[(size_t)px * kCinPad + oc] = f2b(hn);
      }
}

__global__ __launch_bounds__(256) void conv_h_k(const unsigned short* __restrict__ bufT,
                                                const unsigned short* __restrict__ P,
                                                const float* __restrict__ bh,
                                                float* __restrict__ feat) {
  __shared__ float fb[64];
  const int tid = threadIdx.x;
  const int wv = tid >> 6, lane = tid & 63;
  const int y = blockIdx.y, ocBlock = blockIdx.x * 64;
  f32x4 acc[2][2] = {{{0.f,0.f,0.f,0.f},{0.f,0.f,0.f,0.f}},
                     {{0.f,0.f,0.f,0.f},{0.f,0.f,0.f,0.f}}};
  conv_kloop<128, 4, false>(bufT, nullptr, P, y, wv, lane, ocBlock, acc);
  if (tid < 64) fb[tid] = 0.f;
  __syncthreads();
  const int m = lane & 15, kg = lane >> 4;
  const int ocW = ocBlock + (wv >> 1) * 32;
#pragma unroll
  for (int ot = 0; ot < 2; ++ot)
#pragma unroll
    for (int r = 0; r < 4; ++r) {
      const int oc = ocW + ot * 16 + kg * 4 + r;
      const float bv = bh[oc];
      float v = fmaxf(acc[ot][0][r] + bv, 0.f) + fmaxf(acc[ot][1][r] + bv, 0.f);
      v += __shfl_xor(v, 1, 64);
      v += __shfl_xor(v, 2, 64);
      v += __shfl_xor(v, 4, 64);
      v += __shfl_xor(v, 8, 64);
      if (m == 0) atomicAdd(&fb[oc - ocBlock], v);
    }
  __syncthreads();
  if (tid < 64) atomicAdd(&feat[ocBlock + tid], fb[tid]);
}

// ---------------- FC + pose update; zeroes feat ----------------
__global__ void pose_update_k(float* __restrict__ feat, const float* __restrict__ Wfc,
                              const float* __restrict__ bfc, float* __restrict__ pose,
                              float* __restrict__ out) {
  __shared__ float s_d[7];
  int t = threadIdx.x;
  if (t < 7) {
    float s = 0.f;
    const float inv = 1.f / (float)kHW;
    for (int k = 0; k < kHidden; ++k) s += (feat[k] * inv) * Wfc[k * 7 + t];
    s_d[t] = 0.01f * (s + bfc[t]);
  }
  __syncthreads();
  if (t < kHidden) feat[t] = 0.f;
  if (t != 0) return;
  float qc[4] = {pose[0], pose[1], pose[2], pose[3]};
  float tc[3] = {pose[4], pose[5], pose[6]};
  float dq[4] = {1.f + s_d[0], s_d[1], s_d[2], s_d[3]};
  float inv = 1.f / sqrtf(dq[0]*dq[0] + dq[1]*dq[1] + dq[2]*dq[2] + dq[3]*dq[3]);
  dq[0] *= inv; dq[1] *= inv; dq[2] *= inv; dq[3] *= inv;
  float dv[3] = {s_d[4], s_d[5], s_d[6]};
  float rv[3];
  d_qapply(qc, dv, rv);
  float tn[3] = {tc[0] + rv[0], tc[1] + rv[1], tc[2] + rv[2]};
  float qn[4];
  d_qmul(qc, dq, qn);
  float inv2 = 1.f / sqrtf(qn[0]*qn[0] + qn[1]*qn[1] + qn[2]*qn[2] + qn[3]*qn[3]);
  qn[0] *= inv2; qn[1] *= inv2; qn[2] *= inv2; qn[3] *= inv2;
  pose[0] = qn[0]; pose[1] = qn[1]; pose[2] = qn[2]; pose[3] = qn[3];
  pose[4] = tn[0]; pose[5] = tn[1]; pose[6] = tn[2];
  out[0] = qn[0]; out[1] = qn[1]; out[2] = qn[2]; out[3] = qn[3];
  out[4] = tn[0]; out[5] = tn[1]; out[6] = tn[2];
}

// ---------------- launch ----------------
extern "C" void kernel_launch(void* const* d_in, const int* in_sizes, int n_in,
                              void* d_out, int out_size, void* d_ws, size_t ws_size,
                              hipStream_t stream) {
  const float* frgb  = (const float*)d_in[0];
  const float* fdep  = (const float*)d_in[1];
  const float* depth = (const float*)d_in[2];
  const float* ctx   = (const float*)d_in[3];
  const float* intr  = (const float*)d_in[4];
  const float* Wz = (const float*)d_in[5];
  const float* bz = (const float*)d_in[6];
  const float* Wr = (const float*)d_in[7];
  const float* br = (const float*)d_in[8];
  const float* Wq = (const float*)d_in[9];
  const float* bq = (const float*)d_in[10];
  const float* Wh = (const float*)d_in[11];
  const float* bh = (const float*)d_in[12];
  const float* Wfc = (const float*)d_in[13];
  const float* bfc = (const float*)d_in[14];
  float* outp = (float*)d_out;

  float* ws = (float*)d_ws;
  unsigned short* us = (unsigned short*)d_ws;
  unsigned short* corr0 = us + U_CORR0;
  unsigned short* corr1 = us + U_CORR1;
  unsigned short* corr2 = us + U_CORR2;
  unsigned short* corr3 = us + U_CORR3;
  float* X    = ws + F_X;
  float* hbuf = ws + F_H;
  float* zpre = ws + F_ZPRE;
  unsigned short* bufT = us + U_BUFT;
  unsigned short* rhT  = us + U_RHT;
  unsigned short* Pzr  = us + U_PZR;
  unsigned short* Pq   = us + U_PQ;
  unsigned short* Ph   = us + U_PH;
  float* bzr  = ws + F_BZR;
  float* conf = ws + F_CONF;
  float* tkw  = ws + F_TK;
  int*   tki  = (int*)(ws + F_TK + 3);
  float* pose = ws + F_POSE;
  float* feat = ws + F_FEAT;
  unsigned short* fdT  = us + U_FDT;
  unsigned short* qT   = us + U_QT;
  unsigned short* Sbox = us + U_SBOX;  // overlays fdT/qT after setup

  init_k<<<1536, 256, 0, stream>>>(ctx, bz, br, depth, intr, hbuf, bufT, bzr, X,
                                   conf, feat, pose);
  pack_k<<<(kStepsBig * 256 * 4 + 255) / 256, 256, 0, stream>>>(Wz, Wr, 128, 256,
                                                                kStepsBig, 17, kGin, Pzr);
  pack_k<<<(kStepsBig * 128 * 4 + 255) / 256, 256, 0, stream>>>(Wq, Wq, 128, 128,
                                                                kStepsBig, 17, kGin, Pq);
  pack_k<<<(kStepsH * 128 * 4 + 255) / 256, 256, 0, stream>>>(Wh, Wh, 128, 128,
                                                              kStepsH, 4, kHidden, Ph);
  t_bf16_k<<<dim3(48, 4), 256, 0, stream>>>(fdep, fdT);
  t_bf16_k<<<dim3(48, 4), 256, 0, stream>>>(frgb, qT);
  corr_mfma_k<<<dim3(24, 24), 256, 0, stream>>>(fdT, qT, corr0);
  {
    int t1 = kHW * 24 * 32, t2 = kHW * 12 * 16, t3 = kHW * 6 * 8;
    pool2_k<<<(t1 + 255) / 256, 256, 0, stream>>>(corr0, corr1, 48, 64);
    pool2_k<<<(t2 + 255) / 256, 256, 0, stream>>>(corr1, corr2, 24, 32);
    pool2_k<<<(t3 + 255) / 256, 256, 0, stream>>>(corr2, corr3, 12, 16);
  }
  // build box-filtered pyramid in LDS, one block per source pixel
  boxbuild_k<<<kHW, 256, 0, stream>>>(corr0, corr1, corr2, corr3, Sbox);

  for (int it = 0; it < kIters; ++it) {
    conf_k<<<444, 256, 0, stream>>>(Sbox, X, pose, intr, conf);
    topk_k<<<1, 64, 0, stream>>>(conf, tkw, tki);
    fused_k<<<kHW, 256, 0, stream>>>(corr0, corr1, corr2, corr3, X, pose, intr,
                                     tkw, tki, bufT);
    conv_zr_k<<<dim3(4, 48), 256, 0, stream>>>(bufT, Pzr, bzr, zpre, hbuf, rhT);
    conv_q_k<<<dim3(2, 48), 256, 0, stream>>>(bufT, rhT, Pq, bq, zpre, hbuf);
    conv_h_k<<<dim3(2, 48), 256, 0, stream>>>(bufT, Ph, bh, feat);
    pose_update_k<<<1, 128, 0, stream>>>(feat, Wfc, bfc, pose, outp);
  }
}